// Round 4
// baseline (252.950 us; speedup 1.0000x reference)
//
#include <hip/hip_runtime.h>
#include <hip/hip_bf16.h>

#define N 4096
#define DMODEL 128
#define H 4
#define DK 32
#define NSPLIT 8
#define NBLK 512
// q is pre-scaled by (1/sqrt(32)) * log2(e) so all exponentials are raw v_exp_f32 (2^x)
#define QSCALE ((float)(0.17677669529663687 * 1.4426950408889634))

#if __has_builtin(__builtin_amdgcn_exp2f)
#define EXP2(x) __builtin_amdgcn_exp2f(x)
#else
#define EXP2(x) exp2f(x)
#endif

typedef __bf16 bf16x8 __attribute__((ext_vector_type(8)));
typedef __bf16 bf16x4 __attribute__((ext_vector_type(4)));
typedef float f32x4 __attribute__((ext_vector_type(4)));

union SharedU {
  float xs[128 * 8];                                  // proj staging (4 KB)
  float zred[4][32];                                  // z cross-wave reduce
  struct { __bf16 PT[64][72]; float zl[H][64]; } a;   // attn (10.3 KB)
};

// Device-scope grid barrier. Safe: 512 blocks x 256 thr, VGPR<=256 (launch_bounds),
// LDS 10.3KB -> exactly 2 blocks/CU co-resident, so spin always completes.
// Counters are hipMemsetAsync'd to 0 on the stream before launch (deterministic).
__device__ __forceinline__ void grid_barrier(unsigned int* c, int tid) {
  __syncthreads();
  if (tid == 0) {
    __threadfence();  // release: agent-scope L2 writeback
    __hip_atomic_fetch_add(c, 1u, __ATOMIC_RELEASE, __HIP_MEMORY_SCOPE_AGENT);
    while (__hip_atomic_load(c, __ATOMIC_ACQUIRE, __HIP_MEMORY_SCOPE_AGENT) < NBLK)
      __builtin_amdgcn_s_sleep(2);
    __threadfence();  // acquire: invalidate stale caches
  }
  __syncthreads();
}

__global__ __launch_bounds__(256, 2)
void fused_kernel(const float* __restrict__ x,
                  const float* __restrict__ Qw, const float* __restrict__ Qbias,
                  const float* __restrict__ Kw, const float* __restrict__ Kbias,
                  __bf16* __restrict__ qb, __bf16* __restrict__ kb, __bf16* __restrict__ xb,
                  float* __restrict__ Zinv, float* __restrict__ partial,
                  unsigned int* __restrict__ ctr, float* __restrict__ out) {
  __shared__ SharedU sh;
  const int tid = threadIdx.x;
  const int bid = blockIdx.x;
  const int l = tid & 63;
  const int lr = l & 15;
  const int lg = l >> 4;
  const int kc = lg * 8;
  const int wid = tid >> 6;

  // ================= phase 0: projections + x->bf16 (8 n-cols per block) ==========
  {
    const int n0 = bid * 8;
    const int dd = tid >> 1, hh = tid & 1;
    f32x4 v = *(const f32x4*)(x + (size_t)dd * N + n0 + hh * 4);
    ((f32x4*)sh.xs)[tid] = v;
    bf16x4 o;
    o[0] = (__bf16)v[0]; o[1] = (__bf16)v[1]; o[2] = (__bf16)v[2]; o[3] = (__bf16)v[3];
    *(bf16x4*)(xb + (size_t)dd * N + n0 + hh * 4) = o;
    __syncthreads();
    const int a = tid & 127;   // output feature
    const int g = tid >> 7;    // 0 = q, 1 = k
    const float* __restrict__ W = g ? Kw : Qw;
    float acc[8];
    #pragma unroll
    for (int j = 0; j < 8; ++j) acc[j] = 0.f;
    const f32x4* xs4 = (const f32x4*)sh.xs;
    #pragma unroll 4
    for (int d2 = 0; d2 < 128; ++d2) {
      float w = W[d2 * 128 + a];
      f32x4 x0 = xs4[d2 * 2], x1 = xs4[d2 * 2 + 1];
      #pragma unroll
      for (int e = 0; e < 4; ++e) {
        acc[e] += x0[e] * w;
        acc[4 + e] += x1[e] * w;
      }
    }
    const float bias = (g ? Kbias : Qbias)[a];
    const float sc = g ? 1.0f : QSCALE;
    __bf16* __restrict__ dst = g ? kb : qb;
    const int h = a >> 5, c = a & 31;
    #pragma unroll
    for (int j = 0; j < 8; ++j)
      dst[((size_t)h * N + n0 + j) * DK + c] = (__bf16)((acc[j] + bias) * sc);
  }
  grid_barrier(ctr + 0, tid);

  // ================= phase 1: Zinv[h][n] = 1 / sum_m exp2(q~_n . k_m) =============
  // 512 blocks: h = bid>>7, 32 n-rows per block; 4 waves split the m range.
  {
    const int h = bid >> 7;
    const int n0 = (bid & 127) * 32;
    bf16x8 qf[2];
    #pragma unroll
    for (int t = 0; t < 2; ++t)
      qf[t] = *(const bf16x8*)(qb + ((size_t)h * N + n0 + t * 16 + lr) * DK + kc);
    float z[8];
    #pragma unroll
    for (int i = 0; i < 8; ++i) z[i] = 0.f;
    const int mstart = wid * (N / 4);
    #pragma unroll 2
    for (int m0 = mstart; m0 < mstart + N / 4; m0 += 16) {
      bf16x8 kf = *(const bf16x8*)(kb + ((size_t)h * N + m0 + lr) * DK + kc);
      #pragma unroll
      for (int t = 0; t < 2; ++t) {
        f32x4 s = __builtin_amdgcn_mfma_f32_16x16x32_bf16(qf[t], kf, (f32x4){0.f, 0.f, 0.f, 0.f}, 0, 0, 0);
        #pragma unroll
        for (int j = 0; j < 4; ++j) z[t * 4 + j] += EXP2(s[j]);
      }
    }
    #pragma unroll
    for (int off = 1; off < 16; off <<= 1)
      #pragma unroll
      for (int i = 0; i < 8; ++i) z[i] += __shfl_xor(z[i], off, 64);
    if (lr == 0) {
      #pragma unroll
      for (int t = 0; t < 2; ++t)
        #pragma unroll
        for (int j = 0; j < 4; ++j) sh.zred[wid][t * 16 + lg * 4 + j] = z[t * 4 + j];
    }
    __syncthreads();
    if (tid < 32) {
      float s = sh.zred[0][tid] + sh.zred[1][tid] + sh.zred[2][tid] + sh.zred[3][tid];
      Zinv[(size_t)h * N + n0 + tid] = 1.0f / s;
    }
  }
  grid_barrier(ctr + 1, tid);

  // ================= phase 2: partial[sp] += x @ P_mean (64-col m tile) ===========
  // Per-iteration LDS protocol (proven in R2):
  //   zl write -> sync1 -> S phase (reads zl) -> PT write -> sync2 -> PV (reads PT)
  // zl writes of iter i+1 happen after sync2(i) (zl readers done); PT writes of
  // iter i+1 happen after sync1(i+1) (PT readers of iter i done).
  {
    const int mt = bid & 63;
    const int sp = bid >> 6;
    const int m0 = mt * 64;
    const int nstart = sp * (N / NSPLIT);

    bf16x8 kf[H][4];
    #pragma unroll
    for (int h = 0; h < H; ++h)
      #pragma unroll
      for (int t = 0; t < 4; ++t)
        kf[h][t] = *(const bf16x8*)(kb + ((size_t)h * N + m0 + t * 16 + lr) * DK + kc);

    f32x4 acc[2][4];
    #pragma unroll
    for (int dt = 0; dt < 2; ++dt)
      #pragma unroll
      for (int t = 0; t < 4; ++t) acc[dt][t] = (f32x4){0.f, 0.f, 0.f, 0.f};

    for (int n0 = nstart; n0 < nstart + N / NSPLIT; n0 += 64) {
      float zv = Zinv[(size_t)wid * N + n0 + l];
      sh.a.zl[wid][l] = zv;
      __syncthreads();

      float psum[4][4];
      #pragma unroll
      for (int t = 0; t < 4; ++t)
        #pragma unroll
        for (int j = 0; j < 4; ++j) psum[t][j] = 0.f;

      #pragma unroll
      for (int h = 0; h < H; ++h) {
        bf16x8 qf = *(const bf16x8*)(qb + ((size_t)h * N + n0 + wid * 16 + lr) * DK + kc);
        float zi[4];
        #pragma unroll
        for (int j = 0; j < 4; ++j) zi[j] = sh.a.zl[h][wid * 16 + lg * 4 + j];
        #pragma unroll
        for (int t = 0; t < 4; ++t) {
          f32x4 s = __builtin_amdgcn_mfma_f32_16x16x32_bf16(qf, kf[h][t],
                                                            (f32x4){0.f, 0.f, 0.f, 0.f}, 0, 0, 0);
          #pragma unroll
          for (int j = 0; j < 4; ++j)
            psum[t][j] += EXP2(s[j]) * zi[j];
        }
      }
      #pragma unroll
      for (int t = 0; t < 4; ++t)
        #pragma unroll
        for (int j = 0; j < 4; ++j)
          sh.a.PT[t * 16 + lr][wid * 16 + lg * 4 + j] = (__bf16)(psum[t][j] * 0.25f);
      __syncthreads();

      #pragma unroll
      for (int kb2 = 0; kb2 < 2; ++kb2) {
        bf16x8 xa[2];
        #pragma unroll
        for (int dt = 0; dt < 2; ++dt)
          xa[dt] = *(const bf16x8*)(xb + (size_t)(wid * 32 + dt * 16 + lr) * N + n0 + kb2 * 32 + kc);
        #pragma unroll
        for (int t = 0; t < 4; ++t) {
          bf16x8 pf = *(const bf16x8*)(&sh.a.PT[t * 16 + lr][kb2 * 32 + kc]);
          #pragma unroll
          for (int dt = 0; dt < 2; ++dt)
            acc[dt][t] = __builtin_amdgcn_mfma_f32_16x16x32_bf16(xa[dt], pf, acc[dt][t], 0, 0, 0);
        }
      }
    }

    #pragma unroll
    for (int dt = 0; dt < 2; ++dt)
      #pragma unroll
      for (int t = 0; t < 4; ++t)
        #pragma unroll
        for (int j = 0; j < 4; ++j)
          partial[((size_t)sp * DMODEL + wid * 32 + dt * 16 + lg * 4 + j) * N + m0 + t * 16 + lr] =
              acc[dt][t][j];
  }
  grid_barrier(ctr + 2, tid);

  // ================= phase 3: reduce NSPLIT partials -> out =======================
  {
    const int i = bid * 256 + tid;  // f32x4 index over 128*4096/4 = 131072
    const f32x4* p = (const f32x4*)partial;
    f32x4 s = p[i];
    #pragma unroll
    for (int sp = 1; sp < NSPLIT; ++sp) s += p[(size_t)sp * (DMODEL * N / 4) + i];
    ((f32x4*)out)[i] = s;
  }
}

extern "C" void kernel_launch(void* const* d_in, const int* in_sizes, int n_in,
                              void* d_out, int out_size, void* d_ws, size_t ws_size,
                              hipStream_t stream) {
  (void)in_sizes; (void)n_in; (void)out_size; (void)ws_size;
  const float* x  = (const float*)d_in[0];
  const float* Qw = (const float*)d_in[1];
  const float* Qb = (const float*)d_in[2];
  const float* Kw = (const float*)d_in[3];
  const float* Kb = (const float*)d_in[4];

  char* ws = (char*)d_ws;
  __bf16* qb   = (__bf16*)(ws);                          // 1 MB
  __bf16* kb   = (__bf16*)(ws + (1 << 20));              // 1 MB
  __bf16* xb   = (__bf16*)(ws + (2 << 20));              // 1 MB
  float*  Zinv = (float*)(ws + (3 << 20));               // 64 KB
  float*  part = (float*)(ws + (3 << 20) + (1 << 16));   // 16 MB
  unsigned int* ctr = (unsigned int*)(ws + (32 << 20));  // barrier counters
  float*  out  = (float*)d_out;

  hipMemsetAsync(ctr, 0, 64, stream);
  fused_kernel<<<dim3(NBLK), dim3(256), 0, stream>>>(x, Qw, Qb, Kw, Kb, qb, kb, xb,
                                                     Zinv, part, ctr, out);
}

// Round 5
// 50.657 us; speedup vs baseline: 4.9934x; 4.9934x over previous
//
#include <hip/hip_runtime.h>
#include <hip/hip_bf16.h>

#define N 4096
#define DMODEL 128
#define H 4
#define DK 32
#define NSPLIT 8
// q is pre-scaled by (1/sqrt(32)) * log2(e) so all exponentials are raw v_exp_f32 (2^x)
#define QSCALE ((float)(0.17677669529663687 * 1.4426950408889634))

#if __has_builtin(__builtin_amdgcn_exp2f)
#define EXP2(x) __builtin_amdgcn_exp2f(x)
#else
#define EXP2(x) exp2f(x)
#endif

typedef __bf16 bf16x8 __attribute__((ext_vector_type(8)));
typedef __bf16 bf16x4 __attribute__((ext_vector_type(4)));
typedef float f32x4 __attribute__((ext_vector_type(4)));

// ---------------- projections: q~ = (x^T Qw + Qb)*QSCALE, k = x^T Kw + Kb; also x -> bf16 ----
// grid 256 blocks x 256 threads; block owns 16 n-columns. tid&127 = feature, tid>>7 = q/k.
__global__ __launch_bounds__(256, 4)
void proj_kernel(const float* __restrict__ x,
                 const float* __restrict__ Qw, const float* __restrict__ Qbias,
                 const float* __restrict__ Kw, const float* __restrict__ Kbias,
                 __bf16* __restrict__ qb, __bf16* __restrict__ kb, __bf16* __restrict__ xb) {
  __shared__ __align__(16) float xs[128 * 16];  // [d][16 n]
  const int tid = threadIdx.x;
  const int n0 = blockIdx.x * 16;
  #pragma unroll
  for (int it = 0; it < 2; ++it) {
    int idx = tid + it * 256;        // f32x4 index, 512 total
    int dd = idx >> 2, j4 = idx & 3;
    f32x4 v = *(const f32x4*)(x + (size_t)dd * N + n0 + j4 * 4);
    ((f32x4*)xs)[idx] = v;
    bf16x4 o;
    o[0] = (__bf16)v[0]; o[1] = (__bf16)v[1]; o[2] = (__bf16)v[2]; o[3] = (__bf16)v[3];
    *(bf16x4*)(xb + (size_t)dd * N + n0 + j4 * 4) = o;
  }
  __syncthreads();
  const int a = tid & 127;   // output feature 0..127
  const int g = tid >> 7;    // 0 = q, 1 = k
  const float* __restrict__ W = g ? Kw : Qw;
  float acc[16];
  #pragma unroll
  for (int j = 0; j < 16; ++j) acc[j] = 0.f;
  const f32x4* xs4 = (const f32x4*)xs;
  #pragma unroll 8
  for (int dd = 0; dd < 128; ++dd) {
    float w = W[dd * 128 + a];
    #pragma unroll
    for (int jj = 0; jj < 4; ++jj) {
      f32x4 xv = xs4[dd * 4 + jj];
      #pragma unroll
      for (int e = 0; e < 4; ++e) acc[jj * 4 + e] += xv[e] * w;
    }
  }
  const float bias = (g ? Kbias : Qbias)[a];
  const float sc = g ? 1.0f : QSCALE;
  __bf16* __restrict__ dst = g ? kb : qb;
  const int h = a >> 5, c = a & 31;
  #pragma unroll
  for (int j = 0; j < 16; ++j)
    dst[((size_t)h * N + n0 + j) * DK + c] = (__bf16)((acc[j] + bias) * sc);
}

// ---------------- pass 1: Zinv[h][n] = 1 / sum_m exp2(q~_n . k_m) ----------------
// grid: H * N/64 = 256 blocks x 512 threads (8 waves, 2 blocks/CU). Block owns 64 n rows
// (4 q-fragments per wave, k-fragment reused 4x); waves split the m range 8 ways.
__global__ __launch_bounds__(512, 4)
void z_kernel(const __bf16* __restrict__ qb, const __bf16* __restrict__ kb,
              float* __restrict__ Zinv) {
  const int h = blockIdx.x >> 6;
  const int n0 = (blockIdx.x & 63) * 64;
  const int wave = threadIdx.x >> 6;
  const int l = threadIdx.x & 63;
  const int lr = l & 15;
  const int kc = (l >> 4) * 8;
  bf16x8 qf[4];
  #pragma unroll
  for (int t = 0; t < 4; ++t)
    qf[t] = *(const bf16x8*)(qb + ((size_t)h * N + n0 + t * 16 + lr) * DK + kc);
  float z[16];
  #pragma unroll
  for (int i = 0; i < 16; ++i) z[i] = 0.f;
  const int mstart = wave * (N / 8);
  #pragma unroll 4
  for (int m0 = mstart; m0 < mstart + N / 8; m0 += 16) {
    bf16x8 kf = *(const bf16x8*)(kb + ((size_t)h * N + m0 + lr) * DK + kc);
    #pragma unroll
    for (int t = 0; t < 4; ++t) {
      f32x4 s = __builtin_amdgcn_mfma_f32_16x16x32_bf16(qf[t], kf, (f32x4){0.f, 0.f, 0.f, 0.f}, 0, 0, 0);
      #pragma unroll
      for (int j = 0; j < 4; ++j) z[t * 4 + j] += EXP2(s[j]);
    }
  }
  #pragma unroll
  for (int off = 1; off < 16; off <<= 1)
    #pragma unroll
    for (int i = 0; i < 16; ++i) z[i] += __shfl_xor(z[i], off, 64);
  __shared__ float zred[8][64];
  if (lr == 0) {
    int g = l >> 4;
    #pragma unroll
    for (int t = 0; t < 4; ++t)
      #pragma unroll
      for (int j = 0; j < 4; ++j) zred[wave][t * 16 + g * 4 + j] = z[t * 4 + j];
  }
  __syncthreads();
  if (threadIdx.x < 64) {
    int row = threadIdx.x;
    float s = 0.f;
    #pragma unroll
    for (int w = 0; w < 8; ++w) s += zred[w][row];
    Zinv[(size_t)h * N + n0 + row] = 1.0f / s;
  }
}

// ---------------- pass 2: out partial = x @ P_mean for a 64-col m tile, 1/NSPLIT of n ----
// Software-pipelined: next iteration's Zinv + q fragments are loaded during the S phase;
// xa loads issued before sync2 to overlap the barrier. PT writes packed as b64.
__global__ __launch_bounds__(256, 3)
void attn_out_kernel(const __bf16* __restrict__ qb, const __bf16* __restrict__ kb,
                     const __bf16* __restrict__ xb, const float* __restrict__ Zinv,
                     float* __restrict__ partial) {
  const int mt = blockIdx.x & 63;
  const int sp = blockIdx.x >> 6;
  const int m0 = mt * 64;
  const int nstart = sp * (N / NSPLIT);
  const int nend = nstart + N / NSPLIT;
  const int wid = threadIdx.x >> 6;
  const int l = threadIdx.x & 63;
  const int lr = l & 15;
  const int lg = l >> 4;
  const int kc = lg * 8;

  __shared__ __align__(16) __bf16 PT[64][72];  // [m][n], +8 pad
  __shared__ float zl[H][64];

  bf16x8 kf[H][4];
  #pragma unroll
  for (int h = 0; h < H; ++h)
    #pragma unroll
    for (int t = 0; t < 4; ++t)
      kf[h][t] = *(const bf16x8*)(kb + ((size_t)h * N + m0 + t * 16 + lr) * DK + kc);

  f32x4 acc[2][4];
  #pragma unroll
  for (int dt = 0; dt < 2; ++dt)
    #pragma unroll
    for (int t = 0; t < 4; ++t) acc[dt][t] = (f32x4){0.f, 0.f, 0.f, 0.f};

  // prologue prefetch (iteration 0)
  float zv = Zinv[(size_t)wid * N + nstart + l];
  bf16x8 qf[H];
  #pragma unroll
  for (int h = 0; h < H; ++h)
    qf[h] = *(const bf16x8*)(qb + ((size_t)h * N + nstart + wid * 16 + lr) * DK + kc);

  for (int n0 = nstart; n0 < nend; n0 += 64) {
    zl[wid][l] = zv;               // zl readers of prev iter finished before prev sync2
    __syncthreads();               // sync1: zl visible; PT free (prev PV readers done)

    // issue next-iteration prefetch early so it overlaps the S-phase compute
    const int n1 = (n0 + 64 < nend) ? n0 + 64 : nstart;
    float zv_n = Zinv[(size_t)wid * N + n1 + l];
    bf16x8 qf_n[H];
    #pragma unroll
    for (int h = 0; h < H; ++h)
      qf_n[h] = *(const bf16x8*)(qb + ((size_t)h * N + n1 + wid * 16 + lr) * DK + kc);

    // ---- S phase: this wave's 16 n rows, all 4 heads summed in registers ----
    float psum[4][4];
    #pragma unroll
    for (int t = 0; t < 4; ++t)
      #pragma unroll
      for (int j = 0; j < 4; ++j) psum[t][j] = 0.f;

    #pragma unroll
    for (int h = 0; h < H; ++h) {
      float zi[4];
      #pragma unroll
      for (int j = 0; j < 4; ++j) zi[j] = zl[h][wid * 16 + lg * 4 + j];
      #pragma unroll
      for (int t = 0; t < 4; ++t) {
        f32x4 s = __builtin_amdgcn_mfma_f32_16x16x32_bf16(qf[h], kf[h][t],
                                                          (f32x4){0.f, 0.f, 0.f, 0.f}, 0, 0, 0);
        #pragma unroll
        for (int j = 0; j < 4; ++j)
          psum[t][j] += EXP2(s[j]) * zi[j];
      }
    }
    // packed b64 PT writes (cols wid*16+lg*4 .. +3 are contiguous)
    #pragma unroll
    for (int t = 0; t < 4; ++t) {
      bf16x4 pw;
      #pragma unroll
      for (int j = 0; j < 4; ++j) pw[j] = (__bf16)(psum[t][j] * 0.25f);
      *(bf16x4*)(&PT[t * 16 + lr][wid * 16 + lg * 4]) = pw;
    }

    // xa loads don't touch LDS: issue before the barrier to overlap it
    bf16x8 xa[2][2];
    #pragma unroll
    for (int kb2 = 0; kb2 < 2; ++kb2)
      #pragma unroll
      for (int dt = 0; dt < 2; ++dt)
        xa[kb2][dt] = *(const bf16x8*)(xb + (size_t)(wid * 32 + dt * 16 + lr) * N + n0 + kb2 * 32 + kc);
    __syncthreads();               // sync2: PT visible to PV readers

    // ---- PV phase ----
    #pragma unroll
    for (int kb2 = 0; kb2 < 2; ++kb2) {
      #pragma unroll
      for (int t = 0; t < 4; ++t) {
        bf16x8 pf = *(const bf16x8*)(&PT[t * 16 + lr][kb2 * 32 + kc]);
        #pragma unroll
        for (int dt = 0; dt < 2; ++dt)
          acc[dt][t] = __builtin_amdgcn_mfma_f32_16x16x32_bf16(xa[kb2][dt], pf, acc[dt][t], 0, 0, 0);
      }
    }
    zv = zv_n;
    #pragma unroll
    for (int h = 0; h < H; ++h) qf[h] = qf_n[h];
  }

  #pragma unroll
  for (int dt = 0; dt < 2; ++dt)
    #pragma unroll
    for (int t = 0; t < 4; ++t)
      #pragma unroll
      for (int j = 0; j < 4; ++j)
        partial[((size_t)sp * DMODEL + wid * 32 + dt * 16 + lg * 4 + j) * N + m0 + t * 16 + lr] =
            acc[dt][t][j];
}

// ---------------- reduce the NSPLIT partials ----------------
__global__ void reduce_kernel(const float* __restrict__ partial, float* __restrict__ out) {
  int i = blockIdx.x * 256 + threadIdx.x;
  const f32x4* p = (const f32x4*)partial;
  f32x4 s = p[i];
  #pragma unroll
  for (int sp = 1; sp < NSPLIT; ++sp) s += p[(size_t)sp * (DMODEL * N / 4) + i];
  ((f32x4*)out)[i] = s;
}

extern "C" void kernel_launch(void* const* d_in, const int* in_sizes, int n_in,
                              void* d_out, int out_size, void* d_ws, size_t ws_size,
                              hipStream_t stream) {
  (void)in_sizes; (void)n_in; (void)out_size; (void)ws_size;
  const float* x  = (const float*)d_in[0];
  const float* Qw = (const float*)d_in[1];
  const float* Qb = (const float*)d_in[2];
  const float* Kw = (const float*)d_in[3];
  const float* Kb = (const float*)d_in[4];

  char* ws = (char*)d_ws;
  __bf16* qb   = (__bf16*)(ws);                          // 1 MB
  __bf16* kb   = (__bf16*)(ws + (1 << 20));              // 1 MB
  __bf16* xb   = (__bf16*)(ws + (2 << 20));              // 1 MB
  float*  Zinv = (float*)(ws + (3 << 20));               // 64 KB
  float*  part = (float*)(ws + (3 << 20) + (1 << 16));   // 16 MB
  float*  out  = (float*)d_out;

  proj_kernel<<<dim3(N / 16), dim3(256), 0, stream>>>(x, Qw, Qb, Kw, Kb, qb, kb, xb);
  z_kernel<<<dim3(H * (N / 64)), dim3(512), 0, stream>>>(qb, kb, Zinv);
  attn_out_kernel<<<dim3(64 * NSPLIT), dim3(256), 0, stream>>>(qb, kb, xb, Zinv, part);
  reduce_kernel<<<dim3(DMODEL * N / (4 * 256)), dim3(256), 0, stream>>>(part, out);
}